// Round 9
// baseline (96.288 us; speedup 1.0000x reference)
//
#include <hip/hip_runtime.h>
#include <hip/hip_bf16.h>
#include <hip/hip_fp16.h>

// ---------------------------------------------------------------------------
// Modnet2: out[i] = sum_j y_j * ( tanh( tanh(A_i + B_j) @ W2 + b2 ) @ W3 + b3 )
//   A[i][h] = s*(input[i,0:2] @ W1[0:2,h])          (s = 2*log2(e) folded in)
//   B[j][h] = s*(quad_x[j,0:2] @ W1[2:4,h] + b1[h])
//   W2T/b2 pre-scaled by s, so tanh(x) = 1 - 2*rcp(1 + exp2(x_scaled)).
//
// R9: wave-private decomposition, ZERO inner barriers, W2 ENTIRELY IN
// REGISTERS. Each wave owns 16 i x all 128 n: layer-1 tanh computed once
// chip-wide (no duplication), consumed locally (no exchange). W2 = 8nb x 4kc
// half8 frags = 128 VGPR; total ~230 VGPR -> 2 waves/SIMD. LDS = Bs 8KB only
// (one barrier after staging). kc-outer MFMA loop = 8 independent acc chains.
// ---------------------------------------------------------------------------

using fp16x2 = __attribute__((ext_vector_type(2))) __fp16;    // cvt_pkrtz ret
using half8  = __attribute__((ext_vector_type(8))) _Float16;  // MFMA A/B frag
using f32x4  = __attribute__((ext_vector_type(4))) float;     // MFMA C/D frag

#define N_IN   2048
#define M_Q    512
#define H_DIM  128
#define JC     32
#define JCHUNK 16      // M_Q / JC

// ws byte offsets
#define WS_A_OFF     0x000000u   // 2048*128 f32 = 1 MiB   (pre-scaled)
#define WS_B_OFF     0x100000u   //  512*128 f32 = 256 KiB (pre-scaled)
#define WS_Y_OFF     0x140000u   //  512 f32
#define WS_SUMY_OFF  0x140800u   //  1 f32
#define WS_W2T_OFF   0x141000u   //  128*128 f16 = 32 KiB (pre-scaled)
#define WS_SP_OFF    0x150000u   //  32 * 2048 f32 = 256 KiB (n-reduced partials)

#define PI_F   3.14159265358979323846f
#define TSCALE 2.885390081777927f   // 2*log2(e)

// x pre-scaled by TSCALE: tanh = 1 - 2/(1+e^{2x}) = 1 - 2*rcp(1+exp2(xs))
__device__ __forceinline__ float tanh_pre(float xs) {
    float t = __builtin_amdgcn_exp2f(xs);
    float r = __builtin_amdgcn_rcpf(1.0f + t);
    return __builtin_fmaf(-2.0f, r, 1.0f);
}

// one MFMA A-fragment: 8 f16 = tanh(a + b), inputs pre-scaled.
// 4x v_cvt_pkrtz_f16_f32 packs the results (1 instr / 2 elems).
__device__ __forceinline__ void conv8(const float4& a0, const float4& a1,
                                      const float4& b0, const float4& b1,
                                      half8& dst) {
    float t0 = tanh_pre(a0.x + b0.x), t1 = tanh_pre(a0.y + b0.y);
    float t2 = tanh_pre(a0.z + b0.z), t3 = tanh_pre(a0.w + b0.w);
    float t4 = tanh_pre(a1.x + b1.x), t5 = tanh_pre(a1.y + b1.y);
    float t6 = tanh_pre(a1.z + b1.z), t7 = tanh_pre(a1.w + b1.w);
    fp16x2 p[4];
    p[0] = __builtin_amdgcn_cvt_pkrtz(t0, t1);
    p[1] = __builtin_amdgcn_cvt_pkrtz(t2, t3);
    p[2] = __builtin_amdgcn_cvt_pkrtz(t4, t5);
    p[3] = __builtin_amdgcn_cvt_pkrtz(t6, t7);
    __builtin_memcpy(&dst, p, 16);
}

// ---------------------------------------------------------------------------
// k_pre: A, B (scaled), y, sumy, W2T (scaled f16).  grid 257 x 256.
// ---------------------------------------------------------------------------
__global__ void k_pre(const float* __restrict__ input, const float* __restrict__ qx,
                      const float* __restrict__ eq, const float* __restrict__ W1,
                      const float* __restrict__ b1, const float* __restrict__ W2,
                      float* __restrict__ ws) {
    int b = blockIdx.x, t = threadIdx.x;
    float* A = ws + (WS_A_OFF >> 2);
    float* B = ws + (WS_B_OFF >> 2);
    float* Y = ws + (WS_Y_OFF >> 2);
    _Float16* W2T = (_Float16*)((char*)ws + WS_W2T_OFF);

    if (b < 256) {
        int u = b * 256 + t;              // 0..65535
#pragma unroll
        for (int rep = 0; rep < 4; ++rep) {   // A: 262144 elems
            int idx = u + rep * 65536;
            int i = idx >> 7, h = idx & 127;
            A[idx] = TSCALE * (input[2 * i] * W1[h] + input[2 * i + 1] * W1[128 + h]);
        }
        {                                   // B: 65536 elems
            int j = u >> 7, h = u & 127;
            B[u] = TSCALE * (qx[2 * j] * W1[256 + h] + qx[2 * j + 1] * W1[384 + h] + b1[h]);
        }
        if (u < 16384) {                    // W2T[n][k] = f16(s*W2[k][n])
            int n = u >> 7, k = u & 127;
            W2T[u] = (_Float16)(TSCALE * W2[k * 128 + n]);
        }
    } else {                                // y[j], sumy (single block)
        float e = eq[0];
        float s = 0.f;
#pragma unroll
        for (int rep = 0; rep < 2; ++rep) {
            int j = t + rep * 256;
            float yv = sinf(PI_F * e * qx[2 * j]) * sinf(PI_F * e * qx[2 * j + 1]);
            Y[j] = yv;
            s += yv;
        }
        __shared__ float red[4];
        for (int off = 32; off; off >>= 1) s += __shfl_down(s, off);
        if ((t & 63) == 0) red[t >> 6] = s;
        __syncthreads();
        if (t == 0) ws[WS_SUMY_OFF >> 2] = red[0] + red[1] + red[2] + red[3];
    }
}

// ---------------------------------------------------------------------------
// k_main. grid (32 i-blocks, 32 j-chunks) x 256 threads (4 waves).
// Wave w owns rows [blk*64 + w*16, +16), ALL 128 n. W2 in registers.
// mfma_f32_16x16x32_f16 layout (verified R1-R8):
//   A: lane l -> row l&15, k=(l>>4)*8+e ; B: lane l -> col l&15, k=(l>>4)*8+e
//   D: lane l reg r -> row (l>>4)*4+r, col l&15
// ---------------------------------------------------------------------------
__global__ __launch_bounds__(256, 2)
void k_main(const float* __restrict__ A, const float* __restrict__ B,
            const float* __restrict__ Y, const _Float16* __restrict__ W2T,
            const float* __restrict__ b2, const float* __restrict__ W3,
            float* __restrict__ Sp) {
    __shared__ float Bs[JCHUNK * 128];                  // 8 KB
    __shared__ float ys[JCHUNK];

    int t = threadIdx.x;
    int wave = t >> 6, lane = t & 63;
    int l16 = lane & 15, lg = lane >> 4;
    int i0 = blockIdx.x * 64 + wave * 16;
    int jbase = blockIdx.y * JCHUNK;

    // stage B chunk + y into LDS (coalesced)
    for (int o4 = t; o4 < (JCHUNK * 128) >> 2; o4 += 256)
        *(float4*)&Bs[o4 * 4] = *(const float4*)&B[jbase * 128 + o4 * 4];
    if (t < JCHUNK) ys[t] = Y[jbase + t];

    // A-addends for this wave's 16 rows: aa[kc][2]
    float4 aa[4][2];
#pragma unroll
    for (int kc = 0; kc < 4; ++kc) {
        const float* pa = &A[(i0 + l16) * 128 + kc * 32 + lg * 8];
        aa[kc][0] = *(const float4*)pa;
        aa[kc][1] = *(const float4*)(pa + 4);
    }

    // W2 fragments, ALL of W2: wf[nb][kc] = 8*4*4 = 128 VGPR (L2-resident load)
    half8 wf[8][4];
#pragma unroll
    for (int nb = 0; nb < 8; ++nb)
#pragma unroll
        for (int kc = 0; kc < 4; ++kc)
            wf[nb][kc] = *(const half8*)&W2T[(nb * 16 + l16) * 128 + kc * 32 + lg * 8];

    float b2v[8], w3v[8];
#pragma unroll
    for (int nb = 0; nb < 8; ++nb) {
        b2v[nb] = TSCALE * b2[nb * 16 + l16];
        w3v[nb] = W3[nb * 16 + l16];
    }

    __syncthreads();   // Bs/ys ready; no further barriers

    float s[4] = {};   // per-lane W3-folded, y-weighted partials (rows lg*4+r)

#pragma unroll 1
    for (int jj = 0; jj < JCHUNK; ++jj) {
        // layer-1: convert own 16 rows x 128 k once (32 tanh/lane, independent)
        half8 av[4];
#pragma unroll
        for (int kc = 0; kc < 4; ++kc) {
            const float* bp = &Bs[jj * 128 + kc * 32 + lg * 8];
            float4 bj0 = *(const float4*)bp;
            float4 bj1 = *(const float4*)(bp + 4);
            conv8(aa[kc][0], aa[kc][1], bj0, bj1, av[kc]);
        }

        // o = b2 + H1 @ W2 : kc-outer, 8 independent acc chains
        f32x4 o[8];
#pragma unroll
        for (int nb = 0; nb < 8; ++nb) {
            o[nb][0] = b2v[nb]; o[nb][1] = b2v[nb];
            o[nb][2] = b2v[nb]; o[nb][3] = b2v[nb];
        }
#pragma unroll
        for (int kc = 0; kc < 4; ++kc)
#pragma unroll
            for (int nb = 0; nb < 8; ++nb)
                o[nb] = __builtin_amdgcn_mfma_f32_16x16x32_f16(
                    av[kc], wf[nb][kc], o[nb], 0, 0, 0);

        // layer-2 tanh (o pre-scaled) + W3-fold + y-weight
        float yj = ys[jj];
        float wy[8];
#pragma unroll
        for (int nb = 0; nb < 8; ++nb) wy[nb] = w3v[nb] * yj;
#pragma unroll
        for (int nb = 0; nb < 8; ++nb)
#pragma unroll
            for (int r = 0; r < 4; ++r)
                s[r] = __builtin_fmaf(tanh_pre(o[nb][r]), wy[nb], s[r]);
    }

    // epilogue: reduce across the 16 l16 lanes, write partial
#pragma unroll
    for (int m = 1; m < 16; m <<= 1)
#pragma unroll
        for (int r = 0; r < 4; ++r)
            s[r] += __shfl_xor(s[r], m);

    if (l16 == 0) {
        float* dst = Sp + blockIdx.y * N_IN;
#pragma unroll
        for (int r = 0; r < 4; ++r)
            dst[i0 + lg * 4 + r] = s[r];
    }
}

// ---------------------------------------------------------------------------
// k_fin: out[i] = sum_{jc<32} Sp[jc][i] + b3*sumy.  grid 8 x 256.
// ---------------------------------------------------------------------------
__global__ void k_fin(const float* __restrict__ Sp, const float* __restrict__ b3,
                      const float* __restrict__ ws, float* __restrict__ out) {
    int i = blockIdx.x * 256 + threadIdx.x;
    float acc = b3[0] * ws[WS_SUMY_OFF >> 2];
#pragma unroll
    for (int s = 0; s < JC; ++s) acc += Sp[s * N_IN + i];
    out[i] = acc;
}

// ---------------------------------------------------------------------------
extern "C" void kernel_launch(void* const* d_in, const int* in_sizes, int n_in,
                              void* d_out, int out_size, void* d_ws, size_t ws_size,
                              hipStream_t stream) {
    const float* input = (const float*)d_in[0];
    const float* qx    = (const float*)d_in[1];
    const float* eq    = (const float*)d_in[2];
    const float* W1    = (const float*)d_in[3];
    const float* b1    = (const float*)d_in[4];
    const float* W2    = (const float*)d_in[5];
    const float* b2    = (const float*)d_in[6];
    const float* W3    = (const float*)d_in[7];
    const float* b3    = (const float*)d_in[8];
    float* out = (float*)d_out;
    float* ws  = (float*)d_ws;

    const float* A = ws + (WS_A_OFF >> 2);
    const float* B = ws + (WS_B_OFF >> 2);
    const float* Y = ws + (WS_Y_OFF >> 2);
    const _Float16* W2T = (const _Float16*)((char*)d_ws + WS_W2T_OFF);
    float* Sp = (float*)((char*)d_ws + WS_SP_OFF);

    k_pre<<<257, 256, 0, stream>>>(input, qx, eq, W1, b1, W2, ws);
    k_main<<<dim3(32, JC), 256, 0, stream>>>(A, B, Y, W2T, b2, W3, Sp);
    k_fin<<<8, 256, 0, stream>>>(Sp, b3, ws, out);
}

// Round 10
// 94.516 us; speedup vs baseline: 1.0187x; 1.0187x over previous
//
#include <hip/hip_runtime.h>
#include <hip/hip_bf16.h>
#include <hip/hip_fp16.h>

// ---------------------------------------------------------------------------
// Modnet2: out[i] = sum_j y_j * ( tanh( tanh(A_i + B_j) @ W2 + b2 ) @ W3 + b3 )
//   A[i][h] = s*(input[i,0:2] @ W1[0:2,h])          (s = 2*log2(e) folded in)
//   B[j][h] = s*(quad_x[j,0:2] @ W1[2:4,h] + b1[h])
//   W2T/b2 pre-scaled by s, so tanh(x) = 1 - 2*rcp(1 + exp2(x_scaled)).
//
// R10 = R8 (best: 4-wave blocks, wave = 32i x 64n with k-half ownership,
// L1 computed once + dbuf LDS exchange, W2 frags in regs, f16 MFMA, W3
// folded in-loop) + 2j ILP unroll:
//  - conv jA + conv jB back-to-back (64 indep trans chains / lane)
//  - both exchanged per pair through the two xbuf halves
//    (write-barrier-read ... barrier; 2 barriers/pair = same 1/j rate)
//  - MFMA-B overlaps L2-A tanh on separate pipes
//  - L2 fold: s += (-2*y*w3)*rcp ; (1)-part recovered as ysum*sumw3 at end
// ---------------------------------------------------------------------------

using fp16x2 = __attribute__((ext_vector_type(2))) __fp16;    // cvt_pkrtz ret
using half8  = __attribute__((ext_vector_type(8))) _Float16;  // MFMA A/B frag
using f32x4  = __attribute__((ext_vector_type(4))) float;     // MFMA C/D frag

#define N_IN   2048
#define M_Q    512
#define H_DIM  128
#define JC     32
#define JCHUNK 16      // M_Q / JC

// ws byte offsets
#define WS_A_OFF     0x000000u   // 2048*128 f32 = 1 MiB   (pre-scaled)
#define WS_B_OFF     0x100000u   //  512*128 f32 = 256 KiB (pre-scaled)
#define WS_Y_OFF     0x140000u   //  512 f32
#define WS_SUMY_OFF  0x140800u   //  1 f32
#define WS_W2T_OFF   0x141000u   //  128*128 f16 = 32 KiB (pre-scaled)
#define WS_SP_OFF    0x150000u   //  64 * 2048 f32 = 512 KiB (n-reduced partials)

#define PI_F   3.14159265358979323846f
#define TSCALE 2.885390081777927f   // 2*log2(e)

// x pre-scaled by TSCALE: tanh = 1 - 2/(1+e^{2x}) = 1 - 2*rcp(1+exp2(xs))
__device__ __forceinline__ float tanh_pre(float xs) {
    float t = __builtin_amdgcn_exp2f(xs);
    float r = __builtin_amdgcn_rcpf(1.0f + t);
    return __builtin_fmaf(-2.0f, r, 1.0f);
}

// one MFMA A-fragment: 8 f16 = tanh(a + b), inputs pre-scaled.
__device__ __forceinline__ void conv8(const float4& a0, const float4& a1,
                                      const float4& b0, const float4& b1,
                                      half8& dst) {
    float t0 = tanh_pre(a0.x + b0.x), t1 = tanh_pre(a0.y + b0.y);
    float t2 = tanh_pre(a0.z + b0.z), t3 = tanh_pre(a0.w + b0.w);
    float t4 = tanh_pre(a1.x + b1.x), t5 = tanh_pre(a1.y + b1.y);
    float t6 = tanh_pre(a1.z + b1.z), t7 = tanh_pre(a1.w + b1.w);
    fp16x2 p[4];
    p[0] = __builtin_amdgcn_cvt_pkrtz(t0, t1);
    p[1] = __builtin_amdgcn_cvt_pkrtz(t2, t3);
    p[2] = __builtin_amdgcn_cvt_pkrtz(t4, t5);
    p[3] = __builtin_amdgcn_cvt_pkrtz(t6, t7);
    __builtin_memcpy(&dst, p, 16);
}

// ---------------------------------------------------------------------------
// k_pre: A, B (scaled), y, sumy, W2T (scaled f16).  grid 257 x 256.
// ---------------------------------------------------------------------------
__global__ void k_pre(const float* __restrict__ input, const float* __restrict__ qx,
                      const float* __restrict__ eq, const float* __restrict__ W1,
                      const float* __restrict__ b1, const float* __restrict__ W2,
                      float* __restrict__ ws) {
    int b = blockIdx.x, t = threadIdx.x;
    float* A = ws + (WS_A_OFF >> 2);
    float* B = ws + (WS_B_OFF >> 2);
    float* Y = ws + (WS_Y_OFF >> 2);
    _Float16* W2T = (_Float16*)((char*)ws + WS_W2T_OFF);

    if (b < 256) {
        int u = b * 256 + t;              // 0..65535
#pragma unroll
        for (int rep = 0; rep < 4; ++rep) {   // A: 262144 elems
            int idx = u + rep * 65536;
            int i = idx >> 7, h = idx & 127;
            A[idx] = TSCALE * (input[2 * i] * W1[h] + input[2 * i + 1] * W1[128 + h]);
        }
        {                                   // B: 65536 elems
            int j = u >> 7, h = u & 127;
            B[u] = TSCALE * (qx[2 * j] * W1[256 + h] + qx[2 * j + 1] * W1[384 + h] + b1[h]);
        }
        if (u < 16384) {                    // W2T[n][k] = f16(s*W2[k][n])
            int n = u >> 7, k = u & 127;
            W2T[u] = (_Float16)(TSCALE * W2[k * 128 + n]);
        }
    } else {                                // y[j], sumy (single block)
        float e = eq[0];
        float s = 0.f;
#pragma unroll
        for (int rep = 0; rep < 2; ++rep) {
            int j = t + rep * 256;
            float yv = sinf(PI_F * e * qx[2 * j]) * sinf(PI_F * e * qx[2 * j + 1]);
            Y[j] = yv;
            s += yv;
        }
        __shared__ float red[4];
        for (int off = 32; off; off >>= 1) s += __shfl_down(s, off);
        if ((t & 63) == 0) red[t >> 6] = s;
        __syncthreads();
        if (t == 0) ws[WS_SUMY_OFF >> 2] = red[0] + red[1] + red[2] + red[3];
    }
}

// ---------------------------------------------------------------------------
// k_main. grid (32 i-blocks, 32 j-chunks) x 256 threads (4 waves).
// wave w: ih=w>>1 (i-half, 32 rows), p=w&1 (n-half, 64 cols; own k-chunks
// {2p,2p+1}). Pair-unrolled j: both xbuf halves used per pair.
// mfma_f32_16x16x32_f16 layout (verified R1-R8):
//   A: lane l -> row l&15, k=(l>>4)*8+e ; B: lane l -> col l&15, k=(l>>4)*8+e
//   D: lane l reg r -> row (l>>4)*4+r, col l&15
// ---------------------------------------------------------------------------
__global__ __launch_bounds__(256, 2)
void k_main(const float* __restrict__ A, const float* __restrict__ B,
            const float* __restrict__ Y, const _Float16* __restrict__ W2T,
            const float* __restrict__ b2, const float* __restrict__ W3,
            float* __restrict__ Sp) {
    __shared__ float Bs[JCHUNK * 128];                  // 8 KB
    __shared__ float ys[JCHUNK];
    __shared__ _Float16 xbuf[2 * 2 * 4 * 2 * 512];      // half x ih x kc x rb x 1KB = 32 KB

    int t = threadIdx.x;
    int wave = t >> 6, lane = t & 63;
    int l16 = lane & 15, lg = lane >> 4;
    int ih = wave >> 1, p = wave & 1;
    int ibW = blockIdx.x * 64 + ih * 32;
    int jbase = blockIdx.y * JCHUNK;
    int myk0 = 2 * p;                 // own k-chunk base
    int otk0 = 2 * (1 - p);           // partner's k-chunk base

    // stage B chunk + y into LDS (coalesced)
    for (int off4 = t; off4 < (JCHUNK * 128) >> 2; off4 += 256)
        *(float4*)&Bs[off4 * 4] = *(const float4*)&B[jbase * 128 + off4 * 4];
    if (t < JCHUNK) ys[t] = Y[jbase + t];

    // A-addends for OWN k-chunks only: aa[rb][kco][2]
    float4 aa[2][2][2];
#pragma unroll
    for (int rb = 0; rb < 2; ++rb)
#pragma unroll
        for (int kco = 0; kco < 2; ++kco) {
            const float* pa = &A[(ibW + rb * 16 + l16) * 128 + (myk0 + kco) * 32 + lg * 8];
            aa[rb][kco][0] = *(const float4*)pa;
            aa[rb][kco][1] = *(const float4*)(pa + 4);
        }

    // W2 fragments for this wave's 64 n, all 128 k (own-k and partner-k sets)
    half8 wfo[4][2], wfx[4][2];
#pragma unroll
    for (int nb = 0; nb < 4; ++nb)
#pragma unroll
        for (int kco = 0; kco < 2; ++kco) {
            int nrow = (p * 64 + nb * 16 + l16) * 128 + lg * 8;
            wfo[nb][kco] = *(const half8*)&W2T[nrow + (myk0 + kco) * 32];
            wfx[nb][kco] = *(const half8*)&W2T[nrow + (otk0 + kco) * 32];
        }

    float b2v[4], m2w3[4], sumw3 = 0.f;
#pragma unroll
    for (int nb = 0; nb < 4; ++nb) {
        b2v[nb] = TSCALE * b2[p * 64 + nb * 16 + l16];
        float w3 = W3[p * 64 + nb * 16 + l16];
        m2w3[nb] = -2.0f * w3;
        sumw3 += w3;
    }

    _Float16* xw = xbuf + (ih * 4 + myk0) * 2 * 512 + lane * 8;
    _Float16* xr = xbuf + (ih * 4 + otk0) * 2 * 512 + lane * 8;

    __syncthreads();

    float s[2][4] = {};   // in-loop: sum of (-2 y w3) * rcp ; fixed up at end
    float ysum = 0.f;

#pragma unroll 1
    for (int pr = 0; pr < JCHUNK / 2; ++pr) {
        int jA = 2 * pr, jB = 2 * pr + 1;

        // ---- conv both j's own k-chunks: 64 independent trans chains ----
        half8 avA[2][2], avB[2][2];
#pragma unroll
        for (int kco = 0; kco < 2; ++kco) {
            const float* bpA = &Bs[jA * 128 + (myk0 + kco) * 32 + lg * 8];
            float4 bA0 = *(const float4*)bpA;
            float4 bA1 = *(const float4*)(bpA + 4);
            const float* bpB = &Bs[jB * 128 + (myk0 + kco) * 32 + lg * 8];
            float4 bB0 = *(const float4*)bpB;
            float4 bB1 = *(const float4*)(bpB + 4);
#pragma unroll
            for (int rb = 0; rb < 2; ++rb) {
                conv8(aa[rb][kco][0], aa[rb][kco][1], bA0, bA1, avA[kco][rb]);
                conv8(aa[rb][kco][0], aa[rb][kco][1], bB0, bB1, avB[kco][rb]);
            }
        }

        __syncthreads();   // partner finished reading previous pair's xbuf

        // write both: jA -> half 0, jB -> half 1
#pragma unroll
        for (int kco = 0; kco < 2; ++kco)
#pragma unroll
            for (int rb = 0; rb < 2; ++rb) {
                *(half8*)(xw + (kco * 2 + rb) * 512) = avA[kco][rb];
                *(half8*)(xw + 8192 + (kco * 2 + rb) * 512) = avB[kco][rb];
            }

        __syncthreads();   // writes visible

        half8 axA[2][2], axB[2][2];
#pragma unroll
        for (int kco = 0; kco < 2; ++kco)
#pragma unroll
            for (int rb = 0; rb < 2; ++rb) {
                axA[kco][rb] = *(const half8*)(xr + (kco * 2 + rb) * 512);
                axB[kco][rb] = *(const half8*)(xr + 8192 + (kco * 2 + rb) * 512);
            }

        // ---- jA: MFMA then L2-fold ----
        float yA = ys[jA];
        ysum += yA;
        {
            f32x4 o[2][4];
#pragma unroll
            for (int rb = 0; rb < 2; ++rb)
#pragma unroll
                for (int nb = 0; nb < 4; ++nb) {
                    o[rb][nb][0] = b2v[nb]; o[rb][nb][1] = b2v[nb];
                    o[rb][nb][2] = b2v[nb]; o[rb][nb][3] = b2v[nb];
                }
#pragma unroll
            for (int kco = 0; kco < 2; ++kco)
#pragma unroll
                for (int rb = 0; rb < 2; ++rb)
#pragma unroll
                    for (int nb = 0; nb < 4; ++nb)
                        o[rb][nb] = __builtin_amdgcn_mfma_f32_16x16x32_f16(
                            avA[kco][rb], wfo[nb][kco], o[rb][nb], 0, 0, 0);
#pragma unroll
            for (int kco = 0; kco < 2; ++kco)
#pragma unroll
                for (int rb = 0; rb < 2; ++rb)
#pragma unroll
                    for (int nb = 0; nb < 4; ++nb)
                        o[rb][nb] = __builtin_amdgcn_mfma_f32_16x16x32_f16(
                            axA[kco][rb], wfx[nb][kco], o[rb][nb], 0, 0, 0);

            float m2wy[4];
#pragma unroll
            for (int nb = 0; nb < 4; ++nb) m2wy[nb] = m2w3[nb] * yA;
#pragma unroll
            for (int rb = 0; rb < 2; ++rb)
#pragma unroll
                for (int r = 0; r < 4; ++r) {
#pragma unroll
                    for (int nb = 0; nb < 4; ++nb) {
                        float e = __builtin_amdgcn_exp2f(o[rb][nb][r]);
                        float rv = __builtin_amdgcn_rcpf(1.0f + e);
                        s[rb][r] = __builtin_fmaf(m2wy[nb], rv, s[rb][r]);
                    }
                }
        }

        // ---- jB: MFMA then L2-fold ----
        float yB = ys[jB];
        ysum += yB;
        {
            f32x4 o[2][4];
#pragma unroll
            for (int rb = 0; rb < 2; ++rb)
#pragma unroll
                for (int nb = 0; nb < 4; ++nb) {
                    o[rb][nb][0] = b2v[nb]; o[rb][nb][1] = b2v[nb];
                    o[rb][nb][2] = b2v[nb]; o[rb][nb][3] = b2v[nb];
                }
#pragma unroll
            for (int kco = 0; kco < 2; ++kco)
#pragma unroll
                for (int rb = 0; rb < 2; ++rb)
#pragma unroll
                    for (int nb = 0; nb < 4; ++nb)
                        o[rb][nb] = __builtin_amdgcn_mfma_f32_16x16x32_f16(
                            avB[kco][rb], wfo[nb][kco], o[rb][nb], 0, 0, 0);
#pragma unroll
            for (int kco = 0; kco < 2; ++kco)
#pragma unroll
                for (int rb = 0; rb < 2; ++rb)
#pragma unroll
                    for (int nb = 0; nb < 4; ++nb)
                        o[rb][nb] = __builtin_amdgcn_mfma_f32_16x16x32_f16(
                            axB[kco][rb], wfx[nb][kco], o[rb][nb], 0, 0, 0);

            float m2wy[4];
#pragma unroll
            for (int nb = 0; nb < 4; ++nb) m2wy[nb] = m2w3[nb] * yB;
#pragma unroll
            for (int rb = 0; rb < 2; ++rb)
#pragma unroll
                for (int r = 0; r < 4; ++r) {
#pragma unroll
                    for (int nb = 0; nb < 4; ++nb) {
                        float e = __builtin_amdgcn_exp2f(o[rb][nb][r]);
                        float rv = __builtin_amdgcn_rcpf(1.0f + e);
                        s[rb][r] = __builtin_fmaf(m2wy[nb], rv, s[rb][r]);
                    }
                }
        }
    }

    // fix-up the deferred "+1" of tanh: sum_j y_j * sumw3
#pragma unroll
    for (int rb = 0; rb < 2; ++rb)
#pragma unroll
        for (int r = 0; r < 4; ++r)
            s[rb][r] = __builtin_fmaf(ysum, sumw3, s[rb][r]);

    // epilogue: reduce across the 16 l16 lanes, write partial
#pragma unroll
    for (int m = 1; m < 16; m <<= 1)
#pragma unroll
        for (int rb = 0; rb < 2; ++rb)
#pragma unroll
            for (int r = 0; r < 4; ++r)
                s[rb][r] += __shfl_xor(s[rb][r], m);

    if (l16 == 0) {
        float* dst = Sp + (blockIdx.y * 2 + p) * N_IN;
#pragma unroll
        for (int rb = 0; rb < 2; ++rb)
#pragma unroll
            for (int r = 0; r < 4; ++r)
                dst[ibW + rb * 16 + lg * 4 + r] = s[rb][r];
    }
}

// ---------------------------------------------------------------------------
// k_fin: out[i] = sum_{s<64} Sp[s][i] + b3*sumy.  grid 8 x 256.
// ---------------------------------------------------------------------------
__global__ void k_fin(const float* __restrict__ Sp, const float* __restrict__ b3,
                      const float* __restrict__ ws, float* __restrict__ out) {
    int i = blockIdx.x * 256 + threadIdx.x;
    float acc = b3[0] * ws[WS_SUMY_OFF >> 2];
#pragma unroll
    for (int s = 0; s < 2 * JC; ++s) acc += Sp[s * N_IN + i];
    out[i] = acc;
}

// ---------------------------------------------------------------------------
extern "C" void kernel_launch(void* const* d_in, const int* in_sizes, int n_in,
                              void* d_out, int out_size, void* d_ws, size_t ws_size,
                              hipStream_t stream) {
    const float* input = (const float*)d_in[0];
    const float* qx    = (const float*)d_in[1];
    const float* eq    = (const float*)d_in[2];
    const float* W1    = (const float*)d_in[3];
    const float* b1    = (const float*)d_in[4];
    const float* W2    = (const float*)d_in[5];
    const float* b2    = (const float*)d_in[6];
    const float* W3    = (const float*)d_in[7];
    const float* b3    = (const float*)d_in[8];
    float* out = (float*)d_out;
    float* ws  = (float*)d_ws;

    const float* A = ws + (WS_A_OFF >> 2);
    const float* B = ws + (WS_B_OFF >> 2);
    const float* Y = ws + (WS_Y_OFF >> 2);
    const _Float16* W2T = (const _Float16*)((char*)d_ws + WS_W2T_OFF);
    float* Sp = (float*)((char*)d_ws + WS_SP_OFF);

    k_pre<<<257, 256, 0, stream>>>(input, qx, eq, W1, b1, W2, ws);
    k_main<<<dim3(32, JC), 256, 0, stream>>>(A, B, Y, W2T, b2, W3, Sp);
    k_fin<<<8, 256, 0, stream>>>(Sp, b3, ws, out);
}